// Round 11
// baseline (199.906 us; speedup 1.0000x reference)
//
#include <hip/hip_runtime.h>
#include <hip/hip_bf16.h>
#include <cstdint>
#include <cstddef>

// ---------------------------------------------------------------------------
// MultiHeadAttention: B=2, S=2048, E=1024, H=16, D=64. fp32 in/out.
// Pipeline: cvt(f32->bf16, fused) -> QKV GEMM (scatter Q*scale,K,V^T bf16) ->
//           flash attn (swapped QK^T, static max, cvt_pk P, XCD swizzle;
//                       K staged in LDS dbuf, V streamed from L2) ->
//           out GEMM (fp32 + bias).
// Round-10 base; single change: V fragments stream from L2 (issue-early/
// use-late) instead of LDS staging -> cuts LDS-pipe traffic ~40% (the
// measured bottleneck: ~88% LDS-pipe saturation at round 10).
// ---------------------------------------------------------------------------

typedef float f32x4 __attribute__((ext_vector_type(4)));
typedef short s16x8 __attribute__((ext_vector_type(8)));

#define AS1C(p) ((const __attribute__((address_space(1))) void*)(p))
#define AS3(p)  ((__attribute__((address_space(3))) void*)(p))

__device__ __forceinline__ unsigned short f2bf(float f) {
    union { float f; unsigned u; } v; v.f = f;
    return (unsigned short)((v.u + 0x7FFFu + ((v.u >> 16) & 1u)) >> 16);
}

__device__ __forceinline__ float fast_exp2(float x) {
#if __has_builtin(__builtin_amdgcn_exp2f)
    return __builtin_amdgcn_exp2f(x);
#else
    return exp2f(x);
#endif
}

// ---------------------------------------------------------------------------
// fused fp32 -> bf16 convert for 3 tensors (query, w_qkv, w_out)
// ---------------------------------------------------------------------------
__global__ void cvt_bf16_3(const float* __restrict__ a, const float* __restrict__ b,
                           const float* __restrict__ c,
                           unsigned short* __restrict__ oa, unsigned short* __restrict__ ob,
                           unsigned short* __restrict__ oc,
                           int na4, int nb4, int nc4) {
    int j = blockIdx.x * blockDim.x + threadIdx.x;
    const float* s; unsigned short* d;
    if (j < na4) { s = a; d = oa; }
    else {
        j -= na4;
        if (j < nb4) { s = b; d = ob; }
        else { j -= nb4; if (j >= nc4) return; s = c; d = oc; }
    }
    float4 f = reinterpret_cast<const float4*>(s)[j];
    ushort4 o;
    o.x = f2bf(f.x); o.y = f2bf(f.y); o.z = f2bf(f.z); o.w = f2bf(f.w);
    reinterpret_cast<ushort4*>(d)[j] = o;
}

// ---------------------------------------------------------------------------
// GEMM: C[M,N] = A[M,K] @ B[N,K]^T + bias[N]
// MODE 0: scatter bf16 into Q*QSCALE [b,h,s,d], K[b,h,s,d], Vt[b,h,d,s]
// MODE 1: fp32 store to Cf[M,N]
// ---------------------------------------------------------------------------
// softmax scale folded into Q, in base-2 domain: 1/sqrt(64) * log2(e)
#define QSCALE_L2E (0.125f * 1.44269504088896f)

template <int MODE>
__global__ __launch_bounds__(256, 2)
void gemm_bt(const unsigned short* __restrict__ A,
             const unsigned short* __restrict__ B,
             const float* __restrict__ bias,
             float* __restrict__ Cf,
             unsigned short* __restrict__ Qw,
             unsigned short* __restrict__ Kw,
             unsigned short* __restrict__ Vtw,
             int M, int N, int K) {
    constexpr int BK = 32;
    __shared__ unsigned short As[128 * BK];
    __shared__ unsigned short Bs[128 * BK];

    const int tid = threadIdx.x;
    const int wid = tid >> 6, lane = tid & 63;
    const int brow = blockIdx.y * 128, bcol = blockIdx.x * 128;
    const int wr = wid >> 1, wc = wid & 1;

    f32x4 acc[4][4] = {};

    const int kIters = K / BK;
    for (int kt = 0; kt < kIters; ++kt) {
#pragma unroll
        for (int i = 0; i < 2; ++i) {
            const int lb = (wid * 2 + i) * 1024;        // wave-uniform LDS byte base
            const int row = (lb >> 6) + (lane >> 2);    // 64B per row
            const int inrow = (lane & 3) * 16;
            const char* ga = (const char*)A + ((size_t)(brow + row) * K + kt * BK) * 2 + inrow;
            __builtin_amdgcn_global_load_lds(AS1C(ga), AS3((char*)As + lb), 16, 0, 0);
            const char* gb = (const char*)B + ((size_t)(bcol + row) * K + kt * BK) * 2 + inrow;
            __builtin_amdgcn_global_load_lds(AS1C(gb), AS3((char*)Bs + lb), 16, 0, 0);
        }
        __syncthreads();

        s16x8 af[4], bfr[4];
#pragma unroll
        for (int f = 0; f < 4; ++f) {
            af[f]  = *(const s16x8*)((const char*)As + (wr * 64 + f * 16 + (lane & 15)) * 64 + (lane >> 4) * 16);
            bfr[f] = *(const s16x8*)((const char*)Bs + (wc * 64 + f * 16 + (lane & 15)) * 64 + (lane >> 4) * 16);
        }
#pragma unroll
        for (int mf = 0; mf < 4; ++mf)
#pragma unroll
            for (int nf = 0; nf < 4; ++nf)
                acc[mf][nf] = __builtin_amdgcn_mfma_f32_16x16x32_bf16(af[mf], bfr[nf], acc[mf][nf], 0, 0, 0);
        __syncthreads();
    }

    // ---- epilogue ----
    float bv[4];
#pragma unroll
    for (int nf = 0; nf < 4; ++nf) bv[nf] = bias[bcol + wc * 64 + nf * 16 + (lane & 15)];

#pragma unroll
    for (int mf = 0; mf < 4; ++mf) {
#pragma unroll
        for (int r = 0; r < 4; ++r) {
            const int row = brow + wr * 64 + mf * 16 + (lane >> 4) * 4 + r;
#pragma unroll
            for (int nf = 0; nf < 4; ++nf) {
                const int col = bcol + wc * 64 + nf * 16 + (lane & 15);
                float v = acc[mf][nf][r] + bv[nf];
                if constexpr (MODE == 0) {
                    const int which = col >> 10, e = col & 1023;
                    const int h = e >> 6, d = e & 63;
                    const int b = row >> 11, s = row & 2047;
                    const size_t bh = (size_t)(b * 16 + h);
                    if (which == 0)      Qw[(bh * 2048 + s) * 64 + d] = f2bf(v * QSCALE_L2E);
                    else if (which == 1) Kw[(bh * 2048 + s) * 64 + d] = f2bf(v);
                    else                 Vtw[(bh * 64 + d) * 2048 + s] = f2bf(v);
                } else {
                    Cf[(size_t)row * N + col] = v;
                }
            }
        }
    }
}

// ---------------------------------------------------------------------------
// Flash attention fwd. 1D grid of 1024 blocks, XCD-chunked swizzle so each
// XCD owns 4 contiguous bh (2MB K/V -> L2-resident). Block: 256 threads
// (4 waves), each wave owns 16 q-rows. K chunks of 64 keys double-buffered
// in LDS (XOR-swizzled via pre-swizzled global source). V fragments are
// STREAMED per-wave from L2 (global_load_dwordx4), issued at chunk top and
// consumed after QK^T+softmax -> latency hidden, LDS-pipe traffic -40%.
// Swapped QK^T: sacc = mfma(K_frag, Q_frag) = S^T - 16; P -> cvt_pk bf16
// pack + ds_write_b64. Static-max base-2 softmax; l via ones-MFMA.
// ---------------------------------------------------------------------------
__global__ __launch_bounds__(256, 4)
void attn_fwd(const unsigned short* __restrict__ Q,   // [32][2048][64] (pre-scaled)
              const unsigned short* __restrict__ Kk,  // [32][2048][64]
              const unsigned short* __restrict__ Vt,  // [32][64][2048]
              unsigned short* __restrict__ O) {       // [4096][1024] (B,S,E)
    __shared__ unsigned short Ks[2][64 * 64];    // [key][d] swizzled, 2x8KB
    __shared__ unsigned short Ps[4 * 16 * 64];   // per-wave P [16 q][64 key] swizzled, 8KB

    const int tid = threadIdx.x;
    const int wid = tid >> 6, lane = tid & 63;

    // XCD-chunked bijective swizzle: 1024 blocks, 8 XCDs, 128 blocks/XCD.
    // Each XCD covers bh in [xcd*4, xcd*4+4) -> K/V working set 2MB <= L2.
    const int bid = blockIdx.x;
    const int swzb = (bid & 7) * 128 + (bid >> 3);
    const int bh = swzb >> 5;                    // [0,32)
    const int qt = swzb & 31;                    // [0,32)
    const int b = bh >> 4, h = bh & 15;
    const int q0 = qt * 64 + wid * 16;           // first q row for this wave

    const char* Qb  = (const char*)(Q  + (size_t)bh * 2048 * 64);
    const char* Kb  = (const char*)(Kk + (size_t)bh * 2048 * 64);
    const char* Vtb = (const char*)(Vt + (size_t)bh * 64 * 2048);
    char* PsW = (char*)Ps + wid * 2048;          // this wave's P region (16*64*2B)

    const int q = lane & 15, g = lane >> 4;
    const int qswz = (q & 7) << 4;

    // Q fragments: vector index q, k-elems = kf*32 + g*8 .. +8
    s16x8 aq[2];
#pragma unroll
    for (int kf = 0; kf < 2; ++kf)
        aq[kf] = *(const s16x8*)(Qb + (size_t)(q0 + q) * 128 + (kf * 32 + g * 8) * 2);

    f32x4 o_acc[4] = {};
    f32x4 l_acc = {};
    s16x8 ones;
#pragma unroll
    for (int j = 0; j < 8; ++j) ones[j] = (short)0x3F80;  // bf16 1.0

    // stage K chunk [64 keys][64 d] into buf (8 segments of 1KB; 2/wave).
    // LDS rows are 128B; logical byte cb of row stored at (cb ^ ((row&7)<<4)).
    auto stage = [&](int kc, int buf) {
#pragma unroll
        for (int i = 0; i < 2; ++i) {
            const int s = wid * 2 + i;
            const int lb = s * 1024;
            const int row = s * 8 + (lane >> 3);
            const int inrow = (lane & 7) * 16;
            const int srcin = inrow ^ ((row & 7) << 4);
            const char* gk = Kb + (size_t)(kc * 64 + row) * 128 + srcin;
            __builtin_amdgcn_global_load_lds(AS1C(gk), AS3((char*)Ks[buf] + lb), 16, 0, 0);
        }
    };

    stage(0, 0);
    __syncthreads();

    for (int kc = 0; kc < 32; ++kc) {
        const int cur = kc & 1;
        if (kc < 31) stage(kc + 1, cur ^ 1);   // prefetch next K chunk

        // ---- issue V fragment loads NOW (L2-resident; used after softmax) ----
        // bv[kf][df]: B-frag V^T[d = df*16 + q][key = kc*64 + kf*32 + g*8 + j]
        s16x8 bv[2][4];
#pragma unroll
        for (int kf = 0; kf < 2; ++kf)
#pragma unroll
            for (int df = 0; df < 4; ++df)
                bv[kf][df] = *(const s16x8*)(Vtb + (size_t)(df * 16 + q) * 4096 +
                                             (kc * 64 + kf * 32 + g * 8) * 2);

        // ---- S^T = K Q^T - 16 (C-init does the subtract) ----
        // sacc[nf]: value at (key = nf*16 + 4g + r, q-col = q)
        f32x4 sacc[4];
#pragma unroll
        for (int nf = 0; nf < 4; ++nf) sacc[nf] = f32x4{-16.f, -16.f, -16.f, -16.f};
#pragma unroll
        for (int kf = 0; kf < 2; ++kf) {
            s16x8 bk[4];
#pragma unroll
            for (int nf = 0; nf < 4; ++nf) {
                const int key = nf * 16 + q;
                bk[nf] = *(const s16x8*)((const char*)Ks[cur] + key * 128 +
                                         (((kf * 32 + g * 8) * 2) ^ ((key & 7) << 4)));
            }
#pragma unroll
            for (int nf = 0; nf < 4; ++nf)
                sacc[nf] = __builtin_amdgcn_mfma_f32_16x16x32_bf16(bk[nf], aq[kf], sacc[nf], 0, 0, 0);
        }

        // ---- P = exp2(S), pack pairs (v_cvt_pk_bf16_f32), ds_write_b64 ----
        // lane holds keys 16nf+4g+r (r=0..3) for q-row q -> one 8B store per nf.
        {
            char* pbase = PsW + q * 128;
#pragma unroll
            for (int nf = 0; nf < 4; ++nf) {
                float2 lo2 = make_float2(fast_exp2(sacc[nf][0]), fast_exp2(sacc[nf][1]));
                float2 hi2 = make_float2(fast_exp2(sacc[nf][2]), fast_exp2(sacc[nf][3]));
                __hip_bfloat162 plo = __float22bfloat162_rn(lo2);
                __hip_bfloat162 phi = __float22bfloat162_rn(hi2);
                uint2 w;
                w.x = *(unsigned*)&plo;
                w.y = *(unsigned*)&phi;
                const int cb = (nf * 16 + 4 * g) * 2;   // byte of key 16nf+4g in row q
                *(uint2*)(pbase + (cb ^ qswz)) = w;
            }
        }

        // ---- l += P @ 1 ; O += P @ V ----
        s16x8 pa[2];
#pragma unroll
        for (int kf = 0; kf < 2; ++kf)
            pa[kf] = *(const s16x8*)(PsW + q * 128 + (((kf * 32 + g * 8) * 2) ^ qswz));
#pragma unroll
        for (int kf = 0; kf < 2; ++kf) {
            l_acc = __builtin_amdgcn_mfma_f32_16x16x32_bf16(pa[kf], ones, l_acc, 0, 0, 0);
#pragma unroll
            for (int df = 0; df < 4; ++df)
                o_acc[df] = __builtin_amdgcn_mfma_f32_16x16x32_bf16(pa[kf], bv[kf][df], o_acc[df], 0, 0, 0);
        }
        __syncthreads();   // all waves done reading Ks[cur]; next-chunk loads drained here
    }

    // ---- epilogue: O[b][s][h*64+d] = o_acc / l ----
    float inv[4];
#pragma unroll
    for (int r = 0; r < 4; ++r) inv[r] = 1.f / l_acc[r];
#pragma unroll
    for (int df = 0; df < 4; ++df) {
#pragma unroll
        for (int r = 0; r < 4; ++r) {
            const int srow = q0 + g * 4 + r;
            const int dcol = df * 16 + q;
            O[(size_t)(b * 2048 + srow) * 1024 + h * 64 + dcol] = f2bf(o_acc[df][r] * inv[r]);
        }
    }
}

// ---------------------------------------------------------------------------
extern "C" void kernel_launch(void* const* d_in, const int* in_sizes, int n_in,
                              void* d_out, int out_size, void* d_ws, size_t ws_size,
                              hipStream_t stream) {
    const float* query = (const float*)d_in[0];   // [2,2048,1024]
    const float* w_qkv = (const float*)d_in[1];   // [3072,1024]
    const float* b_qkv = (const float*)d_in[2];   // [3072]
    const float* w_out = (const float*)d_in[3];   // [1024,1024]
    const float* b_out = (const float*)d_in[4];   // [1024]
    float* out = (float*)d_out;                   // [2,2048,1024] fp32

    unsigned short* ws = (unsigned short*)d_ws;
    unsigned short* Xbf    = ws;                       // 4096*1024
    unsigned short* Wqkvbf = Xbf + 4096 * 1024;        // 3072*1024
    unsigned short* Woutbf = Wqkvbf + 3072 * 1024;     // 1024*1024
    unsigned short* Qw     = Woutbf + 1024 * 1024;     // 32*2048*64
    unsigned short* Kw     = Qw + 32 * 2048 * 64;
    unsigned short* Vtw    = Kw + 32 * 2048 * 64;
    unsigned short* Obf    = Vtw + 32 * 2048 * 64;     // 4096*1024

    const int na4 = 4096 * 1024 / 4, nb4 = 3072 * 1024 / 4, nc4 = 1024 * 1024 / 4;
    cvt_bf16_3<<<(na4 + nb4 + nc4 + 255) / 256, 256, 0, stream>>>(
        query, w_qkv, w_out, Xbf, Wqkvbf, Woutbf, na4, nb4, nc4);

    gemm_bt<0><<<dim3(3072 / 128, 4096 / 128), 256, 0, stream>>>(
        Xbf, Wqkvbf, b_qkv, nullptr, Qw, Kw, Vtw, 4096, 3072, 1024);

    attn_fwd<<<dim3(1024), 256, 0, stream>>>(Qw, Kw, Vtw, Obf);

    gemm_bt<1><<<dim3(1024 / 128, 4096 / 128), 256, 0, stream>>>(
        Obf, Woutbf, b_out, out, nullptr, nullptr, nullptr, 4096, 1024, 1024);
}

// Round 12
// 132.483 us; speedup vs baseline: 1.5089x; 1.5089x over previous
//
#include <hip/hip_runtime.h>
#include <hip/hip_bf16.h>
#include <cstdint>
#include <cstddef>

// ---------------------------------------------------------------------------
// MultiHeadAttention: B=2, S=2048, E=1024, H=16, D=64. fp32 in/out.
// Pipeline: cvt(f32->bf16, fused) -> QKV GEMM (scatter Q*scale,K,V^T bf16) ->
//           flash attn (swapped QK^T, static max, XCD swizzle; K/V staged in
//                       LDS dbuf; P IN-REGISTER via permlane32+16 swaps) ->
//           out GEMM (fp32 + bias).
// Round-10 base; single change: P never touches LDS. The PV A-fragment is
// built from the QK^T C-layout by the exact 2-swap composition
// (v_permlane32_swap then v_permlane16_swap) -- removes 4 ds_write_b64 +
// 2 ds_read_b128 per wave per chunk from the saturated LDS pipe.
// ---------------------------------------------------------------------------

typedef float f32x4 __attribute__((ext_vector_type(4)));
typedef short s16x8 __attribute__((ext_vector_type(8)));

#define AS1C(p) ((const __attribute__((address_space(1))) void*)(p))
#define AS3(p)  ((__attribute__((address_space(3))) void*)(p))

__device__ __forceinline__ unsigned short f2bf(float f) {
    union { float f; unsigned u; } v; v.f = f;
    return (unsigned short)((v.u + 0x7FFFu + ((v.u >> 16) & 1u)) >> 16);
}

__device__ __forceinline__ float fast_exp2(float x) {
#if __has_builtin(__builtin_amdgcn_exp2f)
    return __builtin_amdgcn_exp2f(x);
#else
    return exp2f(x);
#endif
}

// pack two f32 -> one u32 of 2 bf16 (RNE)
__device__ __forceinline__ unsigned pk_bf2(float lo, float hi) {
    __hip_bfloat162 p = __float22bfloat162_rn(make_float2(lo, hi));
    return *(unsigned*)&p;
}

// ---------------------------------------------------------------------------
// fused fp32 -> bf16 convert for 3 tensors (query, w_qkv, w_out)
// ---------------------------------------------------------------------------
__global__ void cvt_bf16_3(const float* __restrict__ a, const float* __restrict__ b,
                           const float* __restrict__ c,
                           unsigned short* __restrict__ oa, unsigned short* __restrict__ ob,
                           unsigned short* __restrict__ oc,
                           int na4, int nb4, int nc4) {
    int j = blockIdx.x * blockDim.x + threadIdx.x;
    const float* s; unsigned short* d;
    if (j < na4) { s = a; d = oa; }
    else {
        j -= na4;
        if (j < nb4) { s = b; d = ob; }
        else { j -= nb4; if (j >= nc4) return; s = c; d = oc; }
    }
    float4 f = reinterpret_cast<const float4*>(s)[j];
    ushort4 o;
    o.x = f2bf(f.x); o.y = f2bf(f.y); o.z = f2bf(f.z); o.w = f2bf(f.w);
    reinterpret_cast<ushort4*>(d)[j] = o;
}

// ---------------------------------------------------------------------------
// GEMM: C[M,N] = A[M,K] @ B[N,K]^T + bias[N]
// MODE 0: scatter bf16 into Q*QSCALE [b,h,s,d], K[b,h,s,d], Vt[b,h,d,s]
// MODE 1: fp32 store to Cf[M,N]
// ---------------------------------------------------------------------------
// softmax scale folded into Q, in base-2 domain: 1/sqrt(64) * log2(e)
#define QSCALE_L2E (0.125f * 1.44269504088896f)

template <int MODE>
__global__ __launch_bounds__(256, 2)
void gemm_bt(const unsigned short* __restrict__ A,
             const unsigned short* __restrict__ B,
             const float* __restrict__ bias,
             float* __restrict__ Cf,
             unsigned short* __restrict__ Qw,
             unsigned short* __restrict__ Kw,
             unsigned short* __restrict__ Vtw,
             int M, int N, int K) {
    constexpr int BK = 32;
    __shared__ unsigned short As[128 * BK];
    __shared__ unsigned short Bs[128 * BK];

    const int tid = threadIdx.x;
    const int wid = tid >> 6, lane = tid & 63;
    const int brow = blockIdx.y * 128, bcol = blockIdx.x * 128;
    const int wr = wid >> 1, wc = wid & 1;

    f32x4 acc[4][4] = {};

    const int kIters = K / BK;
    for (int kt = 0; kt < kIters; ++kt) {
#pragma unroll
        for (int i = 0; i < 2; ++i) {
            const int lb = (wid * 2 + i) * 1024;        // wave-uniform LDS byte base
            const int row = (lb >> 6) + (lane >> 2);    // 64B per row
            const int inrow = (lane & 3) * 16;
            const char* ga = (const char*)A + ((size_t)(brow + row) * K + kt * BK) * 2 + inrow;
            __builtin_amdgcn_global_load_lds(AS1C(ga), AS3((char*)As + lb), 16, 0, 0);
            const char* gb = (const char*)B + ((size_t)(bcol + row) * K + kt * BK) * 2 + inrow;
            __builtin_amdgcn_global_load_lds(AS1C(gb), AS3((char*)Bs + lb), 16, 0, 0);
        }
        __syncthreads();

        s16x8 af[4], bfr[4];
#pragma unroll
        for (int f = 0; f < 4; ++f) {
            af[f]  = *(const s16x8*)((const char*)As + (wr * 64 + f * 16 + (lane & 15)) * 64 + (lane >> 4) * 16);
            bfr[f] = *(const s16x8*)((const char*)Bs + (wc * 64 + f * 16 + (lane & 15)) * 64 + (lane >> 4) * 16);
        }
#pragma unroll
        for (int mf = 0; mf < 4; ++mf)
#pragma unroll
            for (int nf = 0; nf < 4; ++nf)
                acc[mf][nf] = __builtin_amdgcn_mfma_f32_16x16x32_bf16(af[mf], bfr[nf], acc[mf][nf], 0, 0, 0);
        __syncthreads();
    }

    // ---- epilogue ----
    float bv[4];
#pragma unroll
    for (int nf = 0; nf < 4; ++nf) bv[nf] = bias[bcol + wc * 64 + nf * 16 + (lane & 15)];

#pragma unroll
    for (int mf = 0; mf < 4; ++mf) {
#pragma unroll
        for (int r = 0; r < 4; ++r) {
            const int row = brow + wr * 64 + mf * 16 + (lane >> 4) * 4 + r;
#pragma unroll
            for (int nf = 0; nf < 4; ++nf) {
                const int col = bcol + wc * 64 + nf * 16 + (lane & 15);
                float v = acc[mf][nf][r] + bv[nf];
                if constexpr (MODE == 0) {
                    const int which = col >> 10, e = col & 1023;
                    const int h = e >> 6, d = e & 63;
                    const int b = row >> 11, s = row & 2047;
                    const size_t bh = (size_t)(b * 16 + h);
                    if (which == 0)      Qw[(bh * 2048 + s) * 64 + d] = f2bf(v * QSCALE_L2E);
                    else if (which == 1) Kw[(bh * 2048 + s) * 64 + d] = f2bf(v);
                    else                 Vtw[(bh * 64 + d) * 2048 + s] = f2bf(v);
                } else {
                    Cf[(size_t)row * N + col] = v;
                }
            }
        }
    }
}

// ---------------------------------------------------------------------------
// Flash attention fwd. 1D grid of 1024 blocks, XCD-chunked swizzle so each
// XCD owns 4 contiguous bh (2MB K/V -> L2-resident). Block: 256 threads
// (4 waves), each wave owns 16 q-rows. K/V chunks of 64 keys, double-buffered
// in LDS (XOR-swizzled via pre-swizzled global source).
// Swapped QK^T: sacc = mfma(K_frag, Q_frag) = S^T - 16. P in-register:
// lane (q,g) holds cx[nf] = P-pair keys nf*16+4g+{0,1}, cy[nf] = +{2,3};
// PV A-frag word w = keys kf*32+g*8+2w+{0,1} = tile 2kf+(g>>1) from group
// 2(g&1)+(w>>1). Composition permlane32_swap THEN permlane16_swap on
// (cx[2kf], cx[2kf+1]) yields exactly (word0, word2); same for cy -> 1,3.
// Static-max base-2 softmax; l via ones-MFMA. One barrier per chunk.
// ---------------------------------------------------------------------------
__global__ __launch_bounds__(256, 4)
void attn_fwd(const unsigned short* __restrict__ Q,   // [32][2048][64] (pre-scaled)
              const unsigned short* __restrict__ Kk,  // [32][2048][64]
              const unsigned short* __restrict__ Vt,  // [32][64][2048]
              unsigned short* __restrict__ O) {       // [4096][1024] (B,S,E)
    __shared__ unsigned short Ks[2][64 * 64];    // [key][d] swizzled, 2x8KB
    __shared__ unsigned short Vs[2][64 * 64];    // [d][key] swizzled, 2x8KB

    const int tid = threadIdx.x;
    const int wid = tid >> 6, lane = tid & 63;

    // XCD-chunked bijective swizzle: 1024 blocks, 8 XCDs, 128 blocks/XCD.
    // Each XCD covers bh in [xcd*4, xcd*4+4) -> K/V working set 2MB <= L2.
    const int bid = blockIdx.x;
    const int swzb = (bid & 7) * 128 + (bid >> 3);
    const int bh = swzb >> 5;                    // [0,32)
    const int qt = swzb & 31;                    // [0,32)
    const int b = bh >> 4, h = bh & 15;
    const int q0 = qt * 64 + wid * 16;           // first q row for this wave

    const char* Qb  = (const char*)(Q  + (size_t)bh * 2048 * 64);
    const char* Kb  = (const char*)(Kk + (size_t)bh * 2048 * 64);
    const char* Vtb = (const char*)(Vt + (size_t)bh * 64 * 2048);

    const int q = lane & 15, g = lane >> 4;

    // Q fragments: vector index q, k-elems = kf*32 + g*8 .. +8
    s16x8 aq[2];
#pragma unroll
    for (int kf = 0; kf < 2; ++kf)
        aq[kf] = *(const s16x8*)(Qb + (size_t)(q0 + q) * 128 + (kf * 32 + g * 8) * 2);

    f32x4 o_acc[4] = {};
    f32x4 l_acc = {};
    s16x8 ones;
#pragma unroll
    for (int j = 0; j < 8; ++j) ones[j] = (short)0x3F80;  // bf16 1.0

    // stage K chunk [64 keys][64 d] and Vt chunk [64 d][64 keys] into buf.
    // LDS rows are 128B; logical byte cb of row stored at (cb ^ ((row&7)<<4)).
    auto stage = [&](int kc, int buf) {
#pragma unroll
        for (int i = 0; i < 2; ++i) {
            const int lb = (wid * 2 + i) * 1024;
            const int row = (lb >> 7) + (lane >> 3);
            const int inrow = (lane & 7) * 16;
            const int srcin = inrow ^ ((row & 7) << 4);
            const char* gk = Kb + (size_t)(kc * 64 + row) * 128 + srcin;
            __builtin_amdgcn_global_load_lds(AS1C(gk), AS3((char*)Ks[buf] + lb), 16, 0, 0);
            const char* gv = Vtb + (size_t)row * 4096 + kc * 128 + srcin;
            __builtin_amdgcn_global_load_lds(AS1C(gv), AS3((char*)Vs[buf] + lb), 16, 0, 0);
        }
    };

    stage(0, 0);
    __syncthreads();

    for (int kc = 0; kc < 32; ++kc) {
        const int cur = kc & 1;
        if (kc < 31) stage(kc + 1, cur ^ 1);   // prefetch next chunk

        // ---- S^T = K Q^T - 16 (C-init does the subtract) ----
        // sacc[nf]: value at (key = nf*16 + 4g + r, q-col = q)
        f32x4 sacc[4];
#pragma unroll
        for (int nf = 0; nf < 4; ++nf) sacc[nf] = f32x4{-16.f, -16.f, -16.f, -16.f};
#pragma unroll
        for (int kf = 0; kf < 2; ++kf) {
            s16x8 bk[4];
#pragma unroll
            for (int nf = 0; nf < 4; ++nf) {
                const int key = nf * 16 + q;
                bk[nf] = *(const s16x8*)((const char*)Ks[cur] + key * 128 +
                                         (((kf * 32 + g * 8) * 2) ^ ((key & 7) << 4)));
            }
#pragma unroll
            for (int nf = 0; nf < 4; ++nf)
                sacc[nf] = __builtin_amdgcn_mfma_f32_16x16x32_bf16(bk[nf], aq[kf], sacc[nf], 0, 0, 0);
        }

        // ---- P = exp2(S) in-register; build PV A-frags via 2-swap ----
        // A=cx[2kf], B=cx[2kf+1]: after P32 then P16:
        //   A -> [A0,A2,B0,B2] = word0 (src grp 2(g&1), tile 2kf+(g>>1))
        //   B -> [A1,A3,B1,B3] = word2 (src grp 2(g&1)+1, same tile)
        s16x8 pa[2];
#pragma unroll
        for (int kf = 0; kf < 2; ++kf) {
            unsigned ax = pk_bf2(fast_exp2(sacc[2 * kf][0]),     fast_exp2(sacc[2 * kf][1]));      // cx[2kf]
            unsigned bx = pk_bf2(fast_exp2(sacc[2 * kf + 1][0]), fast_exp2(sacc[2 * kf + 1][1]));  // cx[2kf+1]
            unsigned ay = pk_bf2(fast_exp2(sacc[2 * kf][2]),     fast_exp2(sacc[2 * kf][3]));      // cy[2kf]
            unsigned by = pk_bf2(fast_exp2(sacc[2 * kf + 1][2]), fast_exp2(sacc[2 * kf + 1][3]));  // cy[2kf+1]
            asm("v_permlane32_swap_b32 %0, %1" : "+v"(ax), "+v"(bx));
            asm("v_permlane16_swap_b32 %0, %1" : "+v"(ax), "+v"(bx));
            asm("v_permlane32_swap_b32 %0, %1" : "+v"(ay), "+v"(by));
            asm("v_permlane16_swap_b32 %0, %1" : "+v"(ay), "+v"(by));
            union { s16x8 v; unsigned u[4]; } u;
            u.u[0] = ax; u.u[1] = ay; u.u[2] = bx; u.u[3] = by;
            pa[kf] = u.v;
        }

        // ---- l += P @ 1 ; O += P @ V ----
#pragma unroll
        for (int kf = 0; kf < 2; ++kf) {
            l_acc = __builtin_amdgcn_mfma_f32_16x16x32_bf16(pa[kf], ones, l_acc, 0, 0, 0);
            s16x8 bv[4];
#pragma unroll
            for (int df = 0; df < 4; ++df) {
                const int drow = df * 16 + q;
                bv[df] = *(const s16x8*)((const char*)Vs[cur] + drow * 128 +
                                         (((kf * 32 + g * 8) * 2) ^ ((drow & 7) << 4)));
            }
#pragma unroll
            for (int df = 0; df < 4; ++df)
                o_acc[df] = __builtin_amdgcn_mfma_f32_16x16x32_bf16(pa[kf], bv[df], o_acc[df], 0, 0, 0);
        }
        __syncthreads();   // all waves done reading bufs; next-chunk loads drained here
    }

    // ---- epilogue: O[b][s][h*64+d] = o_acc / l ----
    float inv[4];
#pragma unroll
    for (int r = 0; r < 4; ++r) inv[r] = 1.f / l_acc[r];
#pragma unroll
    for (int df = 0; df < 4; ++df) {
#pragma unroll
        for (int r = 0; r < 4; ++r) {
            const int srow = q0 + g * 4 + r;
            const int dcol = df * 16 + q;
            O[(size_t)(b * 2048 + srow) * 1024 + h * 64 + dcol] = f2bf(o_acc[df][r] * inv[r]);
        }
    }
}

// ---------------------------------------------------------------------------
extern "C" void kernel_launch(void* const* d_in, const int* in_sizes, int n_in,
                              void* d_out, int out_size, void* d_ws, size_t ws_size,
                              hipStream_t stream) {
    const float* query = (const float*)d_in[0];   // [2,2048,1024]
    const float* w_qkv = (const float*)d_in[1];   // [3072,1024]
    const float* b_qkv = (const float*)d_in[2];   // [3072]
    const float* w_out = (const float*)d_in[3];   // [1024,1024]
    const float* b_out = (const float*)d_in[4];   // [1024]
    float* out = (float*)d_out;                   // [2,2048,1024] fp32

    unsigned short* ws = (unsigned short*)d_ws;
    unsigned short* Xbf    = ws;                       // 4096*1024
    unsigned short* Wqkvbf = Xbf + 4096 * 1024;        // 3072*1024
    unsigned short* Woutbf = Wqkvbf + 3072 * 1024;     // 1024*1024
    unsigned short* Qw     = Woutbf + 1024 * 1024;     // 32*2048*64
    unsigned short* Kw     = Qw + 32 * 2048 * 64;
    unsigned short* Vtw    = Kw + 32 * 2048 * 64;
    unsigned short* Obf    = Vtw + 32 * 2048 * 64;     // 4096*1024

    const int na4 = 4096 * 1024 / 4, nb4 = 3072 * 1024 / 4, nc4 = 1024 * 1024 / 4;
    cvt_bf16_3<<<(na4 + nb4 + nc4 + 255) / 256, 256, 0, stream>>>(
        query, w_qkv, w_out, Xbf, Wqkvbf, Woutbf, na4, nb4, nc4);

    gemm_bt<0><<<dim3(3072 / 128, 4096 / 128), 256, 0, stream>>>(
        Xbf, Wqkvbf, b_qkv, nullptr, Qw, Kw, Vtw, 4096, 3072, 1024);

    attn_fwd<<<dim3(1024), 256, 0, stream>>>(Qw, Kw, Vtw, Obf);

    gemm_bt<1><<<dim3(1024 / 128, 4096 / 128), 256, 0, stream>>>(
        Obf, Woutbf, b_out, out, nullptr, nullptr, nullptr, 4096, 1024, 1024);
}